// Round 15
// baseline (325.844 us; speedup 1.0000x reference)
//
#include <hip/hip_runtime.h>
#include <stdint.h>

#define Bdim 16
#define Sdim 4096
#define Hdim 512
#define Mdim (Bdim*Sdim)      // 65536
#define N3   (3*Hdim)         // 1536
#define Kdim 512
#define NCHUNK 128
#define CLEN  (Sdim/NCHUNK)   // 32

typedef __bf16 bf16;
typedef __bf16 bf16x4 __attribute__((ext_vector_type(4)));
typedef __bf16 bf16x8 __attribute__((ext_vector_type(8)));
typedef float  f32x4  __attribute__((ext_vector_type(4)));
typedef _Float16 f16;
typedef _Float16 f16x8 __attribute__((ext_vector_type(8)));

__device__ __forceinline__ void gload_lds16(const void* g, void* l) {
  __builtin_amdgcn_global_load_lds(
      (const __attribute__((address_space(1))) uint32_t*)g,
      (__attribute__((address_space(3))) uint32_t*)l, 16, 0, 0);
}

// ---------- fp32 -> bf16 convert (W only; A is fused into the GEMM) ----------
__global__ void __launch_bounds__(256) cvt_kernel(const float4* __restrict__ in,
                                                  bf16x4* __restrict__ out, int n4) {
  int i = blockIdx.x * blockDim.x + threadIdx.x;
  if (i >= n4) return;
  float4 v = in[i];
  bf16x4 o;
  o.x = (bf16)v.x; o.y = (bf16)v.y; o.z = (bf16)v.z; o.w = (bf16)v.w;
  out[i] = o;
}

// ====== 128x256 MFMA GEMM, 2 blocks/CU, A reg-staged with fused fp32->bf16 ======
// A: (M,K) fp32 row-major -> per step: global fp32 -> regs -> cvt -> ds_write
//    (8KB bf16/step; reg loads issued 2 steps ahead, parity-alternating regs).
// Wb: (N,K) bf16 row-major, staged via global_load_lds (unchanged from r14).
// Simple 2-phase loop + 2 co-resident blocks/CU hide barrier drains (m114).
// Swizzle: 16B slot s^((row>>1)&3) at source AND ds_read (0-conflict, verified).
#define BM 128
#define BN 256
#define BK2 32
#define NT (Kdim/BK2)   // 16
#define LBUF 24576      // per-buffer: A 8KB @0, B 16KB @8192

__global__ void __launch_bounds__(512, 4) gemm_act_kernel(
    const float* __restrict__ Af, const bf16* __restrict__ Wb,
    const float* __restrict__ bias,
    f16* __restrict__ zbuf, f16* __restrict__ fbuf, f16* __restrict__ ogbuf) {
  __shared__ char lds[2 * LBUF];   // 49152 B -> 2 blocks/CU
  const int tid  = threadIdx.x;
  const int wid  = tid >> 6;
  const int lane = tid & 63;
  const int wr = wid >> 2, wc = wid & 3;   // 2(M) x 4(N); wave tile 64x64
  // XCD-chunked bijective swizzle: 3072 blocks = 8 XCDs x 384
  const int bid = blockIdx.x;
  const int wg  = (bid & 7) * 384 + (bid >> 3);
  const int mt = wg / (N3 / BN);           // 512 M-tiles
  const int nt = wg % (N3 / BN);           // 6 N-tiles, inner -> A reuse per XCD
  const int row0 = mt * BM;

  const float* Ag = Af + (size_t)row0 * Kdim;
  const bf16*  Bg = Wb + (size_t)(nt * BN) * Kdim;

  // A reg-staging: 512 bf16 chunks (16B), 1/thread. dest chunk = tid
  // (row = tid>>2, slot = tid&3); source k-window pre-swizzled.
  uint32_t srcA32;
  {
    int row = tid >> 2, slot = tid & 3;
    srcA32 = (uint32_t)(row * Kdim + ((slot ^ ((row >> 1) & 3)) << 3));  // fp32 elems
  }
  // B staging: 1024 chunks, 2/thread, source slot pre-swizzled, dest linear.
  uint32_t srcB[2];
  #pragma unroll
  for (int i = 0; i < 2; ++i) {
    int c = i * 512 + tid;
    int row = c >> 2, slot = c & 3;
    srcB[i] = (uint32_t)(row * Kdim + ((slot ^ ((row >> 1) & 3)) << 3));
  }
  const uint32_t dstBase = (uint32_t)(wid * 1024);  // B DMA dest (+ lane*16 implicit)

  // ds_read byte offsets within a buffer; row stride 64B, kslot = lane>>4
  uint32_t byteA[4], byteB[4];
  {
    int kslot = lane >> 4;
    #pragma unroll
    for (int m = 0; m < 4; ++m) {
      int row = wr * 64 + m * 16 + (lane & 15);
      byteA[m] = (uint32_t)(row * 64 + ((kslot ^ ((row >> 1) & 3)) << 4));
    }
    #pragma unroll
    for (int n = 0; n < 4; ++n) {
      int row = wc * 64 + n * 16 + (lane & 15);
      byteB[n] = (uint32_t)(8192 + row * 64 + ((kslot ^ ((row >> 1) & 3)) << 4));
    }
  }

  f32x4 acc[4][4];
  #pragma unroll
  for (int m = 0; m < 4; ++m)
    #pragma unroll
    for (int n = 0; n < 4; ++n)
      acc[m][n] = (f32x4){0.f, 0.f, 0.f, 0.f};

  float4 ar[2][2];   // in-flight A tile regs, [parity][half]

  #define LOADA(t_, p_) do {                                                 \
    const float* Ap = Ag + srcA32 + (t_) * BK2;                              \
    ar[p_][0] = *(const float4*)(Ap);                                        \
    ar[p_][1] = *(const float4*)(Ap + 4);                                    \
  } while (0)
  #define WRITEA(t_, p_) do {                                                \
    char* Ad = lds + ((t_) & 1) * LBUF;                                      \
    bf16x8 fr;                                                               \
    fr[0] = (bf16)ar[p_][0].x; fr[1] = (bf16)ar[p_][0].y;                    \
    fr[2] = (bf16)ar[p_][0].z; fr[3] = (bf16)ar[p_][0].w;                    \
    fr[4] = (bf16)ar[p_][1].x; fr[5] = (bf16)ar[p_][1].y;                    \
    fr[6] = (bf16)ar[p_][1].z; fr[7] = (bf16)ar[p_][1].w;                    \
    *(bf16x8*)(Ad + tid * 16) = fr;                                          \
  } while (0)

  // prologue: A tile0 -> regs -> LDS; A tile1 -> regs; B tile0 via DMA
  LOADA(0, 0);
  WRITEA(0, 0);       // compiler waits the tile-0 loads here (once)
  LOADA(1, 1);
  {
    char* Bd = lds + 8192;
    #pragma unroll
    for (int i = 0; i < 2; ++i) gload_lds16(Bg + srcB[i], Bd + i * 8192 + dstBase);
  }
  __syncthreads();

  #pragma unroll 2
  for (int t = 0; t < NT; ++t) {
    if (t + 1 < NT) WRITEA(t + 1, (t + 1) & 1);   // regs loaded a full step ago
    if (t + 2 < NT) LOADA(t + 2, t & 1);          // issue; lands during next step
    if (t + 1 < NT) {                             // B DMA for next tile
      char* Bd = lds + ((t + 1) & 1) * LBUF + 8192;
      #pragma unroll
      for (int i = 0; i < 2; ++i)
        gload_lds16(Bg + srcB[i] + (t + 1) * BK2, Bd + i * 8192 + dstBase);
    }
    const char* Ab = lds + (t & 1) * LBUF;
    bf16x8 af[4], bfrag[4];
    #pragma unroll
    for (int m = 0; m < 4; ++m) af[m] = *(const bf16x8*)(Ab + byteA[m]);
    #pragma unroll
    for (int n = 0; n < 4; ++n) bfrag[n] = *(const bf16x8*)(Ab + byteB[n]);
    #pragma unroll
    for (int m = 0; m < 4; ++m)
      #pragma unroll
      for (int n = 0; n < 4; ++n)
        acc[m][n] = __builtin_amdgcn_mfma_f32_16x16x32_bf16(af[m], bfrag[n], acc[m][n], 0, 0, 0);
    __syncthreads();  // drain hidden by the co-resident block's compute
  }

  // ---- epilogue: activation, repack via LDS (32KB), coalesced f16x8 stores ----
  const int gate = nt >> 1;                 // BN=256 divides each 512-col gate
  const int cbn  = (nt & 1) * 256;
  f16* dst = (gate == 0) ? zbuf : ((gate == 1) ? fbuf : ogbuf);
  float bv[4];
  #pragma unroll
  for (int n = 0; n < 4; ++n)
    bv[n] = bias[gate * Hdim + cbn + wc * 64 + n * 16 + (lane & 15)];

  #pragma unroll
  for (int R = 0; R < 2; ++R) {
    // write: waves with wr==R scatter their 64x64 tile (rows R*64..R*64+63)
    if (wr == R) {
      #pragma unroll
      for (int m = 0; m < 4; ++m) {
        #pragma unroll
        for (int n = 0; n < 4; ++n) {
          int col = wc * 64 + n * 16 + (lane & 15);
          #pragma unroll
          for (int r = 0; r < 4; ++r) {
            int Lrow = m * 16 + (lane >> 4) * 4 + r;   // 0..63
            float y = acc[m][n][r] + bv[n];
            float v;
            if (gate == 0) {                       // tanh(y) = 1 - 2/(e^{2y}+1)
              float e = __expf(2.f * y);
              v = 1.f - 2.f / (e + 1.f);
            } else {                               // sigmoid
              v = 1.f / (1.f + __expf(-y));
            }
            uint32_t byte = (uint32_t)(Lrow * 512 + col * 2) ^ ((uint32_t)(Lrow & 7) << 4);
            *(f16*)(lds + byte) = (f16)v;
          }
        }
      }
    }
    __syncthreads();
    // read + coalesced stores: 4 rounds x 512 threads x 16B = 32KB
    #pragma unroll
    for (int j = 0; j < 4; ++j) {
      int c = j * 512 + tid;
      int Lrow = c >> 5, col8 = c & 31;
      uint32_t byte = (uint32_t)(Lrow * 512 + col8 * 16) ^ ((uint32_t)(Lrow & 7) << 4);
      f16x8 v = *(const f16x8*)(lds + byte);
      *(f16x8*)&dst[(size_t)(row0 + R * 64 + Lrow) * Hdim + cbn + col8 * 8] = v;
    }
    __syncthreads();  // reads retired before next round's writes
  }
}

// ---------- scan pass A: f16x8 loads, 8 ch/thread, NCHUNK=128 -> 8 waves/CU ----------
__global__ void __launch_bounds__(256) scanA_kernel(const f16x8* __restrict__ z8,
                                                    const f16x8* __restrict__ f8,
                                                    float* __restrict__ Pb,
                                                    float* __restrict__ Qb) {
  int u  = blockIdx.x * blockDim.x + threadIdx.x;  // 131072 = NCHUNK*B*64
  int ho = u & 63;
  int bc = u >> 6;
  int b  = bc & (Bdim - 1);
  int c  = bc >> 4;
  size_t base = ((size_t)(b * Sdim + c * CLEN)) * 64 + ho;  // in octs
  float P[8], Q[8];
  #pragma unroll
  for (int j = 0; j < 8; ++j) { P[j] = 1.f; Q[j] = 0.f; }
  #pragma unroll 4
  for (int s = 0; s < CLEN; ++s) {
    f16x8 fv = f8[base], zv = z8[base];
    #pragma unroll
    for (int j = 0; j < 8; ++j) {
      float f = (float)fv[j];
      Q[j] += f * ((float)zv[j] - Q[j]);
      P[j] *= (1.f - f);
    }
    base += 64;
  }
  int outi = ((c * Bdim + b) << 9) + ho * 8;
  *(float4*)&Pb[outi]     = make_float4(P[0], P[1], P[2], P[3]);
  *(float4*)&Pb[outi + 4] = make_float4(P[4], P[5], P[6], P[7]);
  *(float4*)&Qb[outi]     = make_float4(Q[0], Q[1], Q[2], Q[3]);
  *(float4*)&Qb[outi + 4] = make_float4(Q[4], Q[5], Q[6], Q[7]);
}

// ---------- scan pass B: scan chunk composites -> h_in per chunk + c_last ----------
__global__ void __launch_bounds__(256) scanB_kernel(const float* __restrict__ Pb,
                                                    const float* __restrict__ Qb,
                                                    float* __restrict__ hin,
                                                    float* __restrict__ c_last) {
  int t = blockIdx.x * blockDim.x + threadIdx.x;  // 8192 = B*H
  int h = t & (Hdim - 1), b = t >> 9;
  float hs = 0.f;
  #pragma unroll 8
  for (int c = 0; c < NCHUNK; ++c) {
    hin[c * (Bdim * Hdim) + t] = hs;
    int u = ((c * Bdim + b) << 9) + h;
    hs = Pb[u] * hs + Qb[u];
  }
  c_last[t] = hs;
}

// ---------- scan pass C: f16x8 loads, fuse out = og * h ----------
__global__ void __launch_bounds__(256) scanC_kernel(const f16x8* __restrict__ z8,
                                                    const f16x8* __restrict__ f8,
                                                    const f16x8* __restrict__ og8,
                                                    const float* __restrict__ hin,
                                                    float4* __restrict__ out4) {
  int u  = blockIdx.x * blockDim.x + threadIdx.x;  // 131072
  int ho = u & 63;
  int bc = u >> 6;
  int b  = bc & (Bdim - 1);
  int c  = bc >> 4;
  const float* hp = &hin[c * (Bdim * Hdim) + b * Hdim + ho * 8];
  float4 h0 = *(const float4*)hp;
  float4 h1 = *(const float4*)(hp + 4);
  float h[8] = {h0.x, h0.y, h0.z, h0.w, h1.x, h1.y, h1.z, h1.w};
  size_t brow = (size_t)(b * Sdim + c * CLEN);
  size_t base = brow * 64 + ho;       // gate octs
  size_t obase = brow * 128 + ho * 2; // out float4s
  #pragma unroll 4
  for (int s = 0; s < CLEN; ++s) {
    f16x8 fv = f8[base], zv = z8[base], ov = og8[base];
    #pragma unroll
    for (int j = 0; j < 8; ++j)
      h[j] += (float)fv[j] * ((float)zv[j] - h[j]);
    out4[obase]     = make_float4((float)ov[0] * h[0], (float)ov[1] * h[1],
                                  (float)ov[2] * h[2], (float)ov[3] * h[3]);
    out4[obase + 1] = make_float4((float)ov[4] * h[4], (float)ov[5] * h[5],
                                  (float)ov[6] * h[6], (float)ov[7] * h[7]);
    base += 64;
    obase += 128;
  }
}

extern "C" void kernel_launch(void* const* d_in, const int* in_sizes, int n_in,
                              void* d_out, int out_size, void* d_ws, size_t ws_size,
                              hipStream_t stream) {
  const float* inp  = (const float*)d_in[0];
  const float* W    = (const float*)d_in[1];
  const float* bias = (const float*)d_in[2];
  float* out = (float*)d_out;

  char* ws = (char*)d_ws;
  bf16* Wbf = (bf16*)(ws + 67108864);        //   1,572,864
  f16*  zh  = (f16*) (ws + 68681728);        //  67,108,864
  f16*  fh  = (f16*) (ws + 135790592);       //  67,108,864
  f16*  ogh = (f16*) (ws + 202899456);       //  67,108,864
  float* Pb = (float*)(ws + 270008320);      //   4,194,304
  float* Qb = (float*)(ws + 274202624);      //   4,194,304
  float* hin= (float*)(ws + 278396928);      //   4,194,304  (peak ~282.6 MB)

  // 1) convert W to bf16 (tiny); A is consumed fp32 by the GEMM (fused cvt)
  {
    int n4 = (N3 * Kdim) / 4;    // 196,608
    cvt_kernel<<<(n4 + 255) / 256, 256, 0, stream>>>((const float4*)W, (bf16x4*)Wbf, n4);
  }
  // 2) GEMM (A reg-staged fused convert) + bias + activations -> fp16 gates
  gemm_act_kernel<<<(Mdim / BM) * (N3 / BN), 512, 0, stream>>>(inp, Wbf, bias,
                                                               zh, fh, ogh);
  // 3) chunked linear-recurrence scan (f16x8 + full occupancy)
  scanA_kernel<<<(NCHUNK * Bdim * 64) / 256, 256, 0, stream>>>(
      (const f16x8*)zh, (const f16x8*)fh, Pb, Qb);
  scanB_kernel<<<(Bdim * Hdim) / 256, 256, 0, stream>>>(Pb, Qb, hin,
                                                        out + (size_t)Mdim * Hdim);
  scanC_kernel<<<(NCHUNK * Bdim * 64) / 256, 256, 0, stream>>>(
      (const f16x8*)zh, (const f16x8*)fh, (const f16x8*)ogh, hin, (float4*)out);
}

// Round 16
// 299.492 us; speedup vs baseline: 1.0880x; 1.0880x over previous
//
#include <hip/hip_runtime.h>
#include <stdint.h>

#define Bdim 16
#define Sdim 4096
#define Hdim 512
#define Mdim (Bdim*Sdim)      // 65536
#define N3   (3*Hdim)         // 1536
#define Kdim 512
#define NCHUNK 128
#define CLEN  (Sdim/NCHUNK)   // 32

typedef __bf16 bf16;
typedef __bf16 bf16x4 __attribute__((ext_vector_type(4)));
typedef __bf16 bf16x8 __attribute__((ext_vector_type(8)));
typedef float  f32x4  __attribute__((ext_vector_type(4)));
typedef _Float16 f16;
typedef _Float16 f16x8 __attribute__((ext_vector_type(8)));

__device__ __forceinline__ void gload_lds16(const void* g, void* l) {
  __builtin_amdgcn_global_load_lds(
      (const __attribute__((address_space(1))) uint32_t*)g,
      (__attribute__((address_space(3))) uint32_t*)l, 16, 0, 0);
}

// ---------- fp32 -> bf16 convert, A and W fused in one dispatch ----------
__global__ void __launch_bounds__(256) cvt2_kernel(const float4* __restrict__ a,
                                                   bf16x4* __restrict__ oa, int nA,
                                                   const float4* __restrict__ w,
                                                   bf16x4* __restrict__ ow, int nW) {
  int i = blockIdx.x * blockDim.x + threadIdx.x;
  const float4* src; bf16x4* dst; int j;
  if (i < nA) { src = a; dst = oa; j = i; }
  else { j = i - nA; if (j >= nW) return; src = w; dst = ow; }
  float4 v = src[j];
  bf16x4 o;
  o.x = (bf16)v.x; o.y = (bf16)v.y; o.z = (bf16)v.z; o.w = (bf16)v.w;
  dst[j] = o;
}

// ====== 128x256 MFMA GEMM, BK=32, 48KB LDS dbuf, acc[4][4] -> 2 blocks/CU ======
// A: (M,K) bf16 row-major; Wb: (N,K) bf16 row-major. C = A*Wb^T, fused act.
// Simple 2-phase loop (stage t+1 -> ds_read t -> MFMA -> __syncthreads);
// 2 co-resident blocks/CU hide each other's barrier/stage drains (m114).
// Swizzle: 16B slot s^((row>>1)&3) at stage source AND ds_read (0-conflict).
#define BM 128
#define BN 256
#define BK2 32
#define NT (Kdim/BK2)   // 16
#define LBUF 24576      // per-buffer: A 8KB @0, B 16KB @8192

__global__ void __launch_bounds__(512, 4) gemm_act_kernel(
    const bf16* __restrict__ A, const bf16* __restrict__ Wb,
    const float* __restrict__ bias,
    f16* __restrict__ zbuf, f16* __restrict__ fbuf, f16* __restrict__ ogbuf) {
  __shared__ char lds[2 * LBUF];   // 49152 B -> 2 blocks/CU
  const int tid  = threadIdx.x;
  const int wid  = tid >> 6;
  const int lane = tid & 63;
  const int wr = wid >> 2, wc = wid & 3;   // 2(M) x 4(N); wave tile 64x64
  // XCD-chunked bijective swizzle: 3072 blocks = 8 XCDs x 384
  const int bid = blockIdx.x;
  const int wg  = (bid & 7) * 384 + (bid >> 3);
  const int mt = wg / (N3 / BN);           // 512 M-tiles
  const int nt = wg % (N3 / BN);           // 6 N-tiles, inner -> A reuse per XCD
  const int row0 = mt * BM;

  const bf16* Ag = A  + (size_t)row0 * Kdim;
  const bf16* Bg = Wb + (size_t)(nt * BN) * Kdim;

  // staging: A = 128 rows x 4 slots x 16B = 8KB = 512 chunks (1/thread);
  //          B = 256 rows x 4 slots = 16KB = 1024 chunks (2/thread).
  // source slot pre-swizzled ^((row>>1)&3); LDS dest linear (chunk*16).
  uint32_t srcA;
  {
    int row = tid >> 2, slot = tid & 3;
    srcA = (uint32_t)(row * Kdim + ((slot ^ ((row >> 1) & 3)) << 3));
  }
  uint32_t srcB[2];
  #pragma unroll
  for (int i = 0; i < 2; ++i) {
    int c = i * 512 + tid;
    int row = c >> 2, slot = c & 3;
    srcB[i] = (uint32_t)(row * Kdim + ((slot ^ ((row >> 1) & 3)) << 3));
  }
  const uint32_t dstBase = (uint32_t)(wid * 1024);  // + lane*16 implicit

  // ds_read byte offsets within a buffer; row stride 64B, kslot = lane>>4
  uint32_t byteA[4], byteB[4];
  {
    int kslot = lane >> 4;
    #pragma unroll
    for (int m = 0; m < 4; ++m) {
      int row = wr * 64 + m * 16 + (lane & 15);
      byteA[m] = (uint32_t)(row * 64 + ((kslot ^ ((row >> 1) & 3)) << 4));
    }
    #pragma unroll
    for (int n = 0; n < 4; ++n) {
      int row = wc * 64 + n * 16 + (lane & 15);
      byteB[n] = (uint32_t)(8192 + row * 64 + ((kslot ^ ((row >> 1) & 3)) << 4));
    }
  }

  f32x4 acc[4][4];
  #pragma unroll
  for (int m = 0; m < 4; ++m)
    #pragma unroll
    for (int n = 0; n < 4; ++n)
      acc[m][n] = (f32x4){0.f, 0.f, 0.f, 0.f};

  // prologue: stage tile 0 into buf0
  {
    char* Ad = lds; char* Bd = lds + 8192;
    gload_lds16(Ag + srcA, Ad + dstBase);
    #pragma unroll
    for (int i = 0; i < 2; ++i) gload_lds16(Bg + srcB[i], Bd + i * 8192 + dstBase);
  }
  __syncthreads();

  for (int t = 0; t < NT; ++t) {
    if (t + 1 < NT) {  // stage next tile into other buffer
      char* Ad = lds + ((t + 1) & 1) * LBUF; char* Bd = Ad + 8192;
      gload_lds16(Ag + srcA + (t + 1) * BK2, Ad + dstBase);
      #pragma unroll
      for (int i = 0; i < 2; ++i)
        gload_lds16(Bg + srcB[i] + (t + 1) * BK2, Bd + i * 8192 + dstBase);
    }
    const char* Ab = lds + (t & 1) * LBUF;
    bf16x8 af[4], bfrag[4];
    #pragma unroll
    for (int m = 0; m < 4; ++m) af[m] = *(const bf16x8*)(Ab + byteA[m]);
    #pragma unroll
    for (int n = 0; n < 4; ++n) bfrag[n] = *(const bf16x8*)(Ab + byteB[n]);
    #pragma unroll
    for (int m = 0; m < 4; ++m)
      #pragma unroll
      for (int n = 0; n < 4; ++n)
        acc[m][n] = __builtin_amdgcn_mfma_f32_16x16x32_bf16(af[m], bfrag[n], acc[m][n], 0, 0, 0);
    __syncthreads();  // drain hidden by the co-resident block's compute
  }

  // ---- epilogue: activation, repack via LDS (32KB), coalesced f16x8 stores ----
  const int gate = nt >> 1;                 // BN=256 divides each 512-col gate
  const int cbn  = (nt & 1) * 256;
  f16* dst = (gate == 0) ? zbuf : ((gate == 1) ? fbuf : ogbuf);
  float bv[4];
  #pragma unroll
  for (int n = 0; n < 4; ++n)
    bv[n] = bias[gate * Hdim + cbn + wc * 64 + n * 16 + (lane & 15)];

  #pragma unroll
  for (int R = 0; R < 2; ++R) {
    // write: waves with wr==R scatter their 64x64 tile (rows R*64..R*64+63)
    if (wr == R) {
      #pragma unroll
      for (int m = 0; m < 4; ++m) {
        #pragma unroll
        for (int n = 0; n < 4; ++n) {
          int col = wc * 64 + n * 16 + (lane & 15);
          #pragma unroll
          for (int r = 0; r < 4; ++r) {
            int Lrow = m * 16 + (lane >> 4) * 4 + r;   // 0..63
            float y = acc[m][n][r] + bv[n];
            float v;
            if (gate == 0) {                       // tanh(y) = 1 - 2/(e^{2y}+1)
              float e = __expf(2.f * y);
              v = 1.f - 2.f / (e + 1.f);
            } else {                               // sigmoid
              v = 1.f / (1.f + __expf(-y));
            }
            uint32_t byte = (uint32_t)(Lrow * 512 + col * 2) ^ ((uint32_t)(Lrow & 7) << 4);
            *(f16*)(lds + byte) = (f16)v;
          }
        }
      }
    }
    __syncthreads();
    // read + coalesced stores: 4 rounds x 512 threads x 16B = 32KB
    #pragma unroll
    for (int j = 0; j < 4; ++j) {
      int c = j * 512 + tid;
      int Lrow = c >> 5, col8 = c & 31;
      uint32_t byte = (uint32_t)(Lrow * 512 + col8 * 16) ^ ((uint32_t)(Lrow & 7) << 4);
      f16x8 v = *(const f16x8*)(lds + byte);
      *(f16x8*)&dst[(size_t)(row0 + R * 64 + Lrow) * Hdim + cbn + col8 * 8] = v;
    }
    __syncthreads();  // reads retired before next round's writes
  }
}

// ---------- scan pass A: f16x8 loads, 8 ch/thread, NCHUNK=128 -> 8 waves/CU ----------
__global__ void __launch_bounds__(256) scanA_kernel(const f16x8* __restrict__ z8,
                                                    const f16x8* __restrict__ f8,
                                                    float* __restrict__ Pb,
                                                    float* __restrict__ Qb) {
  int u  = blockIdx.x * blockDim.x + threadIdx.x;  // 131072 = NCHUNK*B*64
  int ho = u & 63;
  int bc = u >> 6;
  int b  = bc & (Bdim - 1);
  int c  = bc >> 4;
  size_t base = ((size_t)(b * Sdim + c * CLEN)) * 64 + ho;  // in octs
  float P[8], Q[8];
  #pragma unroll
  for (int j = 0; j < 8; ++j) { P[j] = 1.f; Q[j] = 0.f; }
  #pragma unroll 4
  for (int s = 0; s < CLEN; ++s) {
    f16x8 fv = f8[base], zv = z8[base];
    #pragma unroll
    for (int j = 0; j < 8; ++j) {
      float f = (float)fv[j];
      Q[j] += f * ((float)zv[j] - Q[j]);
      P[j] *= (1.f - f);
    }
    base += 64;
  }
  int outi = ((c * Bdim + b) << 9) + ho * 8;
  *(float4*)&Pb[outi]     = make_float4(P[0], P[1], P[2], P[3]);
  *(float4*)&Pb[outi + 4] = make_float4(P[4], P[5], P[6], P[7]);
  *(float4*)&Qb[outi]     = make_float4(Q[0], Q[1], Q[2], Q[3]);
  *(float4*)&Qb[outi + 4] = make_float4(Q[4], Q[5], Q[6], Q[7]);
}

// ---------- scan pass B: scan chunk composites -> h_in per chunk + c_last ----------
__global__ void __launch_bounds__(256) scanB_kernel(const float* __restrict__ Pb,
                                                    const float* __restrict__ Qb,
                                                    float* __restrict__ hin,
                                                    float* __restrict__ c_last) {
  int t = blockIdx.x * blockDim.x + threadIdx.x;  // 8192 = B*H
  int h = t & (Hdim - 1), b = t >> 9;
  float hs = 0.f;
  #pragma unroll 8
  for (int c = 0; c < NCHUNK; ++c) {
    hin[c * (Bdim * Hdim) + t] = hs;
    int u = ((c * Bdim + b) << 9) + h;
    hs = Pb[u] * hs + Qb[u];
  }
  c_last[t] = hs;
}

// ---------- scan pass C: f16x8 loads, fuse out = og * h ----------
__global__ void __launch_bounds__(256) scanC_kernel(const f16x8* __restrict__ z8,
                                                    const f16x8* __restrict__ f8,
                                                    const f16x8* __restrict__ og8,
                                                    const float* __restrict__ hin,
                                                    float4* __restrict__ out4) {
  int u  = blockIdx.x * blockDim.x + threadIdx.x;  // 131072
  int ho = u & 63;
  int bc = u >> 6;
  int b  = bc & (Bdim - 1);
  int c  = bc >> 4;
  const float* hp = &hin[c * (Bdim * Hdim) + b * Hdim + ho * 8];
  float4 h0 = *(const float4*)hp;
  float4 h1 = *(const float4*)(hp + 4);
  float h[8] = {h0.x, h0.y, h0.z, h0.w, h1.x, h1.y, h1.z, h1.w};
  size_t brow = (size_t)(b * Sdim + c * CLEN);
  size_t base = brow * 64 + ho;       // gate octs
  size_t obase = brow * 128 + ho * 2; // out float4s
  #pragma unroll 4
  for (int s = 0; s < CLEN; ++s) {
    f16x8 fv = f8[base], zv = z8[base], ov = og8[base];
    #pragma unroll
    for (int j = 0; j < 8; ++j)
      h[j] += (float)fv[j] * ((float)zv[j] - h[j]);
    out4[obase]     = make_float4((float)ov[0] * h[0], (float)ov[1] * h[1],
                                  (float)ov[2] * h[2], (float)ov[3] * h[3]);
    out4[obase + 1] = make_float4((float)ov[4] * h[4], (float)ov[5] * h[5],
                                  (float)ov[6] * h[6], (float)ov[7] * h[7]);
    base += 64;
    obase += 128;
  }
}

extern "C" void kernel_launch(void* const* d_in, const int* in_sizes, int n_in,
                              void* d_out, int out_size, void* d_ws, size_t ws_size,
                              hipStream_t stream) {
  const float* inp  = (const float*)d_in[0];
  const float* W    = (const float*)d_in[1];
  const float* bias = (const float*)d_in[2];
  float* out = (float*)d_out;

  char* ws = (char*)d_ws;
  bf16* Abf = (bf16*)(ws);                   //  67,108,864
  bf16* Wbf = (bf16*)(ws + 67108864);        //   1,572,864
  f16*  zh  = (f16*) (ws + 68681728);        //  67,108,864
  f16*  fh  = (f16*) (ws + 135790592);       //  67,108,864
  f16*  ogh = (f16*) (ws + 202899456);       //  67,108,864
  float* Pb = (float*)(ws + 270008320);      //   4,194,304
  float* Qb = (float*)(ws + 274202624);      //   4,194,304
  float* hin= (float*)(ws + 278396928);      //   4,194,304  (peak ~282.6 MB)

  // 1) convert A and W to bf16 in one dispatch
  {
    int nA = (Mdim * Kdim) / 4;  // 8,388,608
    int nW = (N3 * Kdim) / 4;    //   196,608
    cvt2_kernel<<<(nA + nW + 255) / 256, 256, 0, stream>>>(
        (const float4*)inp, (bf16x4*)Abf, nA, (const float4*)W, (bf16x4*)Wbf, nW);
  }
  // 2) GEMM + bias + activations -> fp16 gates (128x256, 2 blocks/CU)
  gemm_act_kernel<<<(Mdim / BM) * (N3 / BN), 512, 0, stream>>>(Abf, Wbf, bias,
                                                               zh, fh, ogh);
  // 3) chunked linear-recurrence scan (f16x8 + full occupancy)
  scanA_kernel<<<(NCHUNK * Bdim * 64) / 256, 256, 0, stream>>>(
      (const f16x8*)zh, (const f16x8*)fh, Pb, Qb);
  scanB_kernel<<<(Bdim * Hdim) / 256, 256, 0, stream>>>(Pb, Qb, hin,
                                                        out + (size_t)Mdim * Hdim);
  scanC_kernel<<<(NCHUNK * Bdim * 64) / 256, 256, 0, stream>>>(
      (const f16x8*)zh, (const f16x8*)fh, (const f16x8*)ogh, hin, (float4*)out);
}